// Round 19
// baseline (147.484 us; speedup 1.0000x reference)
//
#include <hip/hip_runtime.h>
#include <hip/hip_bf16.h>
#include <cstdint>

// ---------------------------------------------------------------------------
// Binarized CNN. Verified numerics (R5-R18 passed bit-exact):
//  - binarize(x) == sign(x) exactly; layers 2-4 are exact small-int math in
//    any order -> any packing / instruction choice is safe.
//  - conv1: each accumulator chain MUST sum in (ky,kx,ic)-ascending order
//    (Eigen/XLA-CPU im2col). Chains independent; fma == mul+add (w in +-1/0).
//    DO NOT reorder WITHIN a chain. Pad value 1.0.
//  - k2/k3: MFMA i32_32x32x32_i8 per-tap GEMM, weights-as-A epilogue (R18).
//  - k4: dot4 2x2 (R12). k1: oc-paired pk_fma (R13).
//  - R19: k1 weight loads restructured — per-op bulk copy of 27 f32x2 into
//    SGPR-resident wop[] from a 256B-aligned padded table (32 pairs/op).
//    Was: 108 individual s_load_dwordx2 per thread (K$-throughput bound,
//    ~14K scalar loads/CU). Now: ~4 wide s_loads per op. Values identical.
// ---------------------------------------------------------------------------

typedef __attribute__((ext_vector_type(2)))  float f32x2;
typedef __attribute__((ext_vector_type(4)))  int int4v;
typedef __attribute__((ext_vector_type(16))) int int16v;

#define WOFF_W2M 0          // int[9*64*4] = 9216 B (MFMA frag table L2)
#define WOFF_W3M 10240      // int[9*64*4] = 9216 B (MFMA frag table L3)
#define WOFF_W4P 20480      // int[2*8*9]  =  576 B (dot4 packs L4)
#define WOFF_W1D 28672      // f32x2[4*32] = 1024 B (padded {w2o,w2o+1} pairs)
#define WEIGHTS_BYTES 32768

#define A1_PB (2*256*256*4)     // bytes per batch (packed u32, 4 ch/dword)
#define A2_PB (4*254*254*4)
#define A3_PB (8*252*252*4)

__device__ __forceinline__ int dot4(int a, int b, int c) {
#if __has_builtin(__builtin_amdgcn_sdot4)
    return __builtin_amdgcn_sdot4(a, b, c, false);
#else
    int s = c;
#pragma unroll
    for (int j = 0; j < 4; ++j) {
        int av = (a << (24 - 8 * j)) >> 24;
        int bv = (b << (24 - 8 * j)) >> 24;
        s += av * bv;
    }
    return s;
#endif
}

__device__ __forceinline__ int fsign(float w) {
    return (w > 0.f) ? 1 : ((w < 0.f) ? -1 : 0);
}

// acc.lo += w.lo * v.lo ; acc.hi += w.hi * v.lo   (broadcast LOW of src1)
__device__ __forceinline__ void pkfma_lo(f32x2& acc, f32x2 w, f32x2 v) {
    asm("v_pk_fma_f32 %0, %1, %2, %0 op_sel:[0,0,0] op_sel_hi:[1,0,1]"
        : "+v"(acc) : "s"(w), "v"(v));
}
// acc.lo += w.lo * v.hi ; acc.hi += w.hi * v.hi   (broadcast HIGH of src1)
__device__ __forceinline__ void pkfma_hi(f32x2& acc, f32x2 w, f32x2 v) {
    asm("v_pk_fma_f32 %0, %1, %2, %0 op_sel:[0,1,0] op_sel_hi:[1,1,1]"
        : "+v"(acc) : "s"(w), "v"(v));
}

// ---- weight prep: 3 blocks (one per table group) -------------------------
__global__ __launch_bounds__(256) void kprep(const float* __restrict__ w1,
                                             const float* __restrict__ w2,
                                             const float* __restrict__ w3,
                                             const float* __restrict__ w4,
                                             int* __restrict__ w2m,
                                             int* __restrict__ w3m,
                                             int* __restrict__ w4p,
                                             f32x2* __restrict__ w1d) {
    int tid = threadIdx.x;
    int b = blockIdx.x;
    if (b == 0) {
        for (int idx = tid; idx < 576; idx += 256) {
            int t = idx / 64, l = idx % 64;
            int oc = l & 31, icb = (l >> 5) * 16;
            int wd[4] = {0, 0, 0, 0};
            for (int j = 0; j < 16; ++j) {
                int ic = icb + j;
                int s = (oc < 16 && ic < 8) ? fsign(w2[(oc * 8 + ic) * 9 + t]) : 0;
                wd[j >> 2] |= (s & 0xff) << (8 * (j & 3));
            }
            w2m[idx * 4 + 0] = wd[0]; w2m[idx * 4 + 1] = wd[1];
            w2m[idx * 4 + 2] = wd[2]; w2m[idx * 4 + 3] = wd[3];
        }
    } else if (b == 1) {
        for (int idx = tid; idx < 576; idx += 256) {
            int t = idx / 64, l = idx % 64;
            int oc = l & 31, icb = (l >> 5) * 16;
            int wd[4] = {0, 0, 0, 0};
            for (int j = 0; j < 16; ++j) {
                int ic = icb + j;
                int s = (ic < 16) ? fsign(w3[(oc * 16 + ic) * 9 + t]) : 0;
                wd[j >> 2] |= (s & 0xff) << (8 * (j & 3));
            }
            w3m[idx * 4 + 0] = wd[0]; w3m[idx * 4 + 1] = wd[1];
            w3m[idx * 4 + 2] = wd[2]; w3m[idx * 4 + 3] = wd[3];
        }
    } else {
        for (int idx = tid; idx < 2 * 8 * 9; idx += 256) {
            int k = idx % 9, icg = (idx / 9) % 8, oc = idx / 72;
            int pack = 0;
#pragma unroll
            for (int j = 0; j < 4; ++j)
                pack |= (fsign(w4[(oc * 32 + icg * 4 + j) * 9 + k]) & 0xff) << (8 * j);
            w4p[idx] = pack;
        }
        // padded table: w1d[op*32 + t] (t<27), 256B-aligned per op block
        for (int i = tid; i < 128; i += 256) {
            int op = i / 32, t = i % 32;
            f32x2 pr = {0.f, 0.f};
            if (t < 27) {
                float wa = w1[(2 * op) * 27 + t];
                float wbv = w1[(2 * op + 1) * 27 + t];
                pr[0] = (wa > 0.f) ? 1.f : ((wa < 0.f) ? -1.f : 0.f);
                pr[1] = (wbv > 0.f) ? 1.f : ((wbv < 0.f) ? -1.f : 0.f);
            }
            w1d[i] = pr;
        }
    }
}

// ---- layer 1: pad(1)+conv(3->8)+hardtanh+maxpool2+sign, packed out -------
// R19: per-op weight block bulk-copied into SGPR array (wide s_loads).
// Chains strict (ky,kx,ic)-ascending per contract (verified).
__global__ __launch_bounds__(256, 4) void k1(const float* __restrict__ x,
                                             const f32x2* __restrict__ w1d,
                                             uint32_t* __restrict__ a1, int n0) {
    int ox = threadIdx.x;   // 0..255
    int oy = blockIdx.y;    // 0..255
    int ln = blockIdx.z;
    const float* xn = x + (size_t)(n0 + ln) * 3 * 512 * 512;

    // window as NON-overlapping column pairs: P[ic][r][j] = {col 2j, col 2j+1}
    f32x2 P[3][4][2];
    int iy0 = 2 * oy - 1, ix0 = 2 * ox - 1;

    if (oy > 0 && oy < 255 && ox > 0 && ox < 255) {
#pragma unroll
        for (int ic = 0; ic < 3; ++ic) {
            const float* xc = xn + (size_t)ic * 512 * 512;
#pragma unroll
            for (int r = 0; r < 4; ++r) {
                const float* rp = xc + (size_t)(iy0 + r) * 512 + ix0;
                float a = rp[0];
                float2 m = *(const float2*)(rp + 1);   // cols 1,2 (aligned)
                float b = rp[3];
                P[ic][r][0] = (f32x2){a, m.x};
                P[ic][r][1] = (f32x2){m.y, b};
            }
        }
    } else {
        for (int ic = 0; ic < 3; ++ic) {
            const float* xc = xn + (size_t)ic * 512 * 512;
#pragma unroll
            for (int r = 0; r < 4; ++r) {
                int iy = iy0 + r;
                bool yok = ((unsigned)iy < 512u);
                float t[4];
#pragma unroll
                for (int c = 0; c < 4; ++c) {
                    int ix = ix0 + c;
                    t[c] = (yok && ((unsigned)ix < 512u))
                               ? xc[(size_t)iy * 512 + ix] : 1.0f;
                }
                P[ic][r][0] = (f32x2){t[0], t[1]};
                P[ic][r][1] = (f32x2){t[2], t[3]};
            }
        }
    }

#define PKTAP(ACC, ROW, COL)                                         \
    do {                                                             \
        if (((COL) & 1) == 0) pkfma_lo(ACC, ww, P[ic][ROW][(COL) >> 1]); \
        else                  pkfma_hi(ACC, ww, P[ic][ROW][(COL) >> 1]); \
    } while (0)

    uint64_t dall = 0;
#pragma unroll 1
    for (int op = 0; op < 4; ++op) {
        const f32x2* wb = w1d + op * 32;
        // bulk copy -> contiguous uniform loads merge into wide s_loads;
        // constant indices after unroll -> SGPR-resident array
        f32x2 wop[27];
#pragma unroll
        for (int t = 0; t < 27; ++t) wop[t] = wb[t];

        f32x2 a00 = {0.f, 0.f}, a01 = {0.f, 0.f};
        f32x2 a10 = {0.f, 0.f}, a11 = {0.f, 0.f};
#pragma unroll
        for (int ky = 0; ky < 3; ++ky) {
#pragma unroll
            for (int kx = 0; kx < 3; ++kx) {
#pragma unroll
                for (int ic = 0; ic < 3; ++ic) {
                    f32x2 ww = wop[ic * 9 + ky * 3 + kx];
                    PKTAP(a00, ky + 0, kx + 0);
                    PKTAP(a01, ky + 0, kx + 1);
                    PKTAP(a10, ky + 1, kx + 0);
                    PKTAP(a11, ky + 1, kx + 1);
                }
            }
        }
        float m0 = fmaxf(fmaxf(a00[0], a01[0]), fmaxf(a10[0], a11[0]));
        float m1 = fmaxf(fmaxf(a00[1], a01[1]), fmaxf(a10[1], a11[1]));
        int s0 = (m0 > 0.f) ? 1 : ((m0 < 0.f) ? -1 : 0);
        int s1 = (m1 > 0.f) ? 1 : ((m1 < 0.f) ? -1 : 0);
        dall |= (uint64_t)(uint32_t)(s0 & 0xff) << (8 * (2 * op));
        dall |= (uint64_t)(uint32_t)(s1 & 0xff) << (8 * (2 * op + 1));
    }
#undef PKTAP

    uint32_t d0 = (uint32_t)dall;
    uint32_t d1 = (uint32_t)(dall >> 32);
    size_t base = (((size_t)ln * 2) * 256 + oy) * 256 + ox;
    a1[base]             = d0;
    a1[base + 256 * 256] = d1;
}

// ---- layers 2/3: ternary conv via MFMA i32_32x32x32_i8 -------------------
// R18: operands swapped (weights=A, acts=B) -> C[row=oc, col=px]; in-register
// epilogue, direct global stores. R16: 8 rows/block, 10 staged rows.
template<int ICG, int INW, int OUTW, int OCGO>
__global__ __launch_bounds__(256) void kconv(const uint32_t* __restrict__ ain,
                                             const int* __restrict__ wm,
                                             uint32_t* __restrict__ aout) {
    __shared__ uint32_t stb[10][36][4];    // [row][x][icg], rows y0..y0+9
    constexpr int LG = (ICG == 2) ? 1 : 2;
    int w    = threadIdx.x >> 6;
    int lane = threadIdx.x & 63;
    int x0 = blockIdx.x * 32;
    int y0 = blockIdx.y * 8;
    int ln = blockIdx.z;

    const int4v* wmv = (const int4v*)wm;
    int4v bfr[9];
#pragma unroll
    for (int t = 0; t < 9; ++t) bfr[t] = wmv[t * 64 + lane];

    const uint32_t* abase = ain + (size_t)ln * ICG * INW * INW;
    for (int idx = threadIdx.x; idx < 10 * 36 * ICG; idx += 256) {
        int icg = idx & (ICG - 1);
        int r2 = idx >> LG;
        int xx = r2 % 36, row = r2 / 36;
        int gy = y0 + row, gx = x0 + xx;
        uint32_t val = 0;
        if (xx < 34 && gx < INW && gy < INW)
            val = abase[((size_t)icg * INW + gy) * INW + gx];
        stb[row][xx][icg] = val;
    }
    __syncthreads();

    int xl = lane & 31;
    int h  = lane >> 5;

#pragma unroll
    for (int ry = 0; ry < 2; ++ry) {
        int yy = y0 + 2 * w + ry;
        int16v acc = {};
#pragma unroll
        for (int ky = 0; ky < 3; ++ky) {
#pragma unroll
            for (int kx = 0; kx < 3; ++kx) {
                int4v a = *(const int4v*)&stb[2 * w + ry + ky][xl + kx][0];
                acc = __builtin_amdgcn_mfma_i32_32x32x32_i8(bfr[ky * 3 + kx], a, acc, 0, 0, 0);
            }
        }
        bool ok = (yy < OUTW) && (x0 + xl < OUTW);
#pragma unroll
        for (int g = 0; g < 4; ++g) {
            int ocg = 2 * g + h;              // oc = 8g + 4h + j, byte j
            if (ocg < OCGO && ok) {
                uint32_t dw = 0;
#pragma unroll
                for (int j = 0; j < 4; ++j) {
                    int v = min(max(acc[4 * g + j], -1), 1);
                    dw |= (uint32_t)(v & 0xff) << (8 * j);
                }
                aout[(((size_t)ln * OCGO + ocg) * OUTW + yy) * OUTW + x0 + xl] = dw;
            }
        }
    }
}

// ---- layer 4: conv(32->2) ternary, dot4, 2x2 outputs/thread, f32 out -----
__global__ __launch_bounds__(128) void k4(const uint32_t* __restrict__ a3,
                                          const int* __restrict__ w4p,
                                          float* __restrict__ out, int n0) {
    int ox = threadIdx.x; if (ox >= 125) return;
    int oy0 = blockIdx.y * 2;
    int ln = blockIdx.z;

    int acc[2][2][2] = {};
#pragma unroll
    for (int icg = 0; icg < 8; ++icg) {
        uint32_t r[4][4];
        const uint32_t* base = a3 + (((size_t)ln * 8 + icg) * 252 + oy0) * 252 + 2 * ox;
#pragma unroll
        for (int j = 0; j < 4; ++j) {
            uint2 lo = *(const uint2*)(base + (size_t)j * 252);
            uint2 hi = *(const uint2*)(base + (size_t)j * 252 + 2);
            r[j][0] = lo.x; r[j][1] = lo.y; r[j][2] = hi.x; r[j][3] = hi.y;
        }
#pragma unroll
        for (int o = 0; o < 2; ++o) {
            const int* wb = w4p + ((o * 8 + icg) * 9);
#pragma unroll
            for (int ky = 0; ky < 3; ++ky) {
#pragma unroll
                for (int p = 0; p < 2; ++p) {
#pragma unroll
                    for (int q = 0; q < 2; ++q) {
                        acc[p][q][o] = dot4((int)r[p + ky][q + 0], wb[ky * 3 + 0], acc[p][q][o]);
                        acc[p][q][o] = dot4((int)r[p + ky][q + 1], wb[ky * 3 + 1], acc[p][q][o]);
                        acc[p][q][o] = dot4((int)r[p + ky][q + 2], wb[ky * 3 + 2], acc[p][q][o]);
                    }
                }
            }
        }
    }
    size_t gn = (size_t)(n0 + ln);
#pragma unroll
    for (int o = 0; o < 2; ++o)
#pragma unroll
        for (int p = 0; p < 2; ++p) {
            float2 w;
            w.x = fminf(fmaxf((float)acc[p][0][o], -1.f), 1.f);
            w.y = fminf(fmaxf((float)acc[p][1][o], -1.f), 1.f);
            *(float2*)(out + ((gn * 2 + o) * 250 + (oy0 + p)) * 250 + 2 * ox) = w;
        }
}

extern "C" void kernel_launch(void* const* d_in, const int* in_sizes, int n_in,
                              void* d_out, int out_size, void* d_ws, size_t ws_size,
                              hipStream_t stream) {
    const float* x  = (const float*)d_in[0];
    const float* w1 = (const float*)d_in[1];
    const float* w2 = (const float*)d_in[2];
    const float* w3 = (const float*)d_in[3];
    const float* w4 = (const float*)d_in[4];
    char* ws = (char*)d_ws;

    int*   w2m = (int*)(ws + WOFF_W2M);
    int*   w3m = (int*)(ws + WOFF_W3M);
    int*   w4p = (int*)(ws + WOFF_W4P);
    f32x2* w1d = (f32x2*)(ws + WOFF_W1D);
    float* out = (float*)d_out;

    size_t per = (size_t)A1_PB + (size_t)A2_PB + (size_t)A3_PB;
    int NC = 32;
    while (NC > 1 && (size_t)WEIGHTS_BYTES + (size_t)NC * per > ws_size) NC >>= 1;

    uint32_t* A1 = (uint32_t*)(ws + WEIGHTS_BYTES);
    uint32_t* A2 = (uint32_t*)(ws + WEIGHTS_BYTES + (size_t)NC * A1_PB);
    uint32_t* A3 = (uint32_t*)(ws + WEIGHTS_BYTES + (size_t)NC * (A1_PB + A2_PB));

    kprep<<<dim3(3), 256, 0, stream>>>(w1, w2, w3, w4, w2m, w3m, w4p, w1d);
    for (int n0 = 0; n0 < 32; n0 += NC) {
        k1<<<dim3(1, 256, NC), 256, 0, stream>>>(x, w1d, A1, n0);
        kconv<2, 256, 254, 4><<<dim3(8, 32, NC), 256, 0, stream>>>(A1, w2m, A2);
        kconv<4, 254, 252, 8><<<dim3(8, 32, NC), 256, 0, stream>>>(A2, w3m, A3);
        k4<<<dim3(1, 125, NC), 128, 0, stream>>>(A3, w4p, out, n0);
    }
}